// Round 3
// baseline (467.047 us; speedup 1.0000x reference)
//
#include <hip/hip_runtime.h>
#include <stdint.h>

#define NHEADS 8
#define NTOK   3137
#define BATCH  16
#define CDIM   512
#define MT     (BATCH*NTOK)   // 50192

typedef unsigned short u16;
typedef float f32x4  __attribute__((ext_vector_type(4)));
typedef short bf16x8 __attribute__((ext_vector_type(8)));

__device__ __forceinline__ float bf2f(u16 u){
  union { uint32_t i; float f; } x; x.i = ((uint32_t)u) << 16; return x.f;
}
__device__ __forceinline__ u16 f2bf(float f){
  union { float f; uint32_t i; } x; x.f = f;
  uint32_t r = x.i + 0x7fffu + ((x.i >> 16) & 1u);
  return (u16)(r >> 16);
}
__device__ __forceinline__ void async_ld16(void* lds, const void* g){
  __builtin_amdgcn_global_load_lds((const __attribute__((address_space(1))) void*)g,
                                   (__attribute__((address_space(3))) void*)lds, 16, 0, 0);
}
#define BARM()   asm volatile("s_barrier" ::: "memory")
#define WAITV(N) asm volatile("s_waitcnt vmcnt(" #N ")" ::: "memory")
#define MFMA16(d,a,b) d = __builtin_amdgcn_mfma_f32_16x16x32_bf16(a,b,d,0,0,0)

// ---------------- K0: fp32 -> bf16 cast ----------------
__global__ void cvt_kernel(const float* __restrict__ src, u16* __restrict__ dst, int n4){
  int i = blockIdx.x * blockDim.x + threadIdx.x;
  if (i < n4){
    float4 v = ((const float4*)src)[i];
    uint32_t lo = ((uint32_t)f2bf(v.y) << 16) | f2bf(v.x);
    uint32_t hi = ((uint32_t)f2bf(v.w) << 16) | f2bf(v.z);
    ((uint2*)dst)[i] = make_uint2(lo, hi);
  }
}

// ---------------- GEMM: 8-phase counted-vmcnt schedule (T3+T4+T5, m201-class) ----------------
// C[m][o] = sum_k A[m][k]*Bw[o][k] + bias[o], K=512, BK=64, 256x256 tile, 8 waves (2Mx4N).
// LDS per buffer: A0|A1|B0|B1 regions (128x64 bf16 each, 16KB); 2 buffers = 128KB.
// Wave output 128x64 spans BOTH A-halves (rows wr*64+[0,64) of each) and BOTH B-halves
// (cols wc*32+[0,32) of each) so each region has a last-reader phase:
//   P1: rd A0,B0  (stage A1(t+1))   P2: rd A1 (stage B1(t+1))  [B0 dead]
//   P3: rd B1     (stage B0(t+2))   [A0 dead]
//   P4: -         (stage A0(t+2)) ; s_waitcnt vmcnt(4) ; barrier   [A1,B1 dead]
// Raw s_barrier (asm, memory clobber) — never __syncthreads (would drain vmcnt(0)).
// MODE 0: scatter bf16 to q/k/v [b*8+h][n][64].  MODE 1: fp32 out [m][512].
template<int MODE>
__global__ __launch_bounds__(512, 2) void gemm8(
    const u16* __restrict__ A, const u16* __restrict__ Bw, const float* __restrict__ bias,
    u16* __restrict__ q_s, u16* __restrict__ k_s, u16* __restrict__ v_s,
    float* __restrict__ outF, int M)
{
  __shared__ __align__(16) u16 smem[65536];   // 128 KiB
  const int t = threadIdx.x;
  const int w = t >> 6, l = t & 63;
  const int wr = w >> 2, wc = w & 3;          // 2 x 4 waves
  const int lr = l & 15, lg = l >> 4;

  // T1: bijective XCD-aware remap (m204)
  const int nx = gridDim.x;
  const int nwg = nx * gridDim.y;
  const int orig = blockIdx.y * nx + blockIdx.x;
  const int q8 = nwg >> 3, r8 = nwg & 7;
  const int xcd = orig & 7;
  const int wgid = (xcd < r8 ? xcd*(q8+1) : r8*(q8+1) + (xcd-r8)*q8) + (orig >> 3);
  const int n0 = (wgid % nx) * 256;
  const int m0 = (wgid / nx) * 256;

  f32x4 acc[8][4];
#pragma unroll
  for (int i=0;i<8;i++)
#pragma unroll
    for (int j=0;j<4;j++) acc[i][j] = (f32x4){0.f,0.f,0.f,0.f};

  // stage one 128x64 half-tile (2 loads/thread). region: 0=A0 1=A1 2=B0 3=B1
  auto stageH = [&](int buf, int region, int k0){
    u16* dst = smem + buf*32768 + region*8192;
#pragma unroll
    for (int j=0;j<2;j++){
      int qc = t + 512*j;                 // 0..1023 : R=row(0..127), c=chunk(0..7)
      int R = qc >> 3, c = qc & 7;
      int cs = (c ^ (R & 7)) * 8;         // pre-swizzled global source (rule #21)
      if (region < 2){
        int ar = m0 + region*128 + R; if (ar > M-1) ar = M-1;
        async_ld16(&dst[qc*8], &A[(size_t)ar*512 + k0 + cs]);
      } else {
        int br = n0 + (region-2)*128 + R;
        async_ld16(&dst[qc*8], &Bw[(size_t)br*512 + k0 + cs]);
      }
    }
  };
  auto rdA = [&](int buf, int mh, int f, int ks)->bf16x8 {
    int row = wr*64 + f*16 + lr;
    int chunk = ks*4 + lg;
    return *(const bf16x8*)&smem[buf*32768 + mh*8192 + row*64 + ((chunk ^ (row&7))*8)];
  };
  auto rdB = [&](int buf, int nh, int g, int ks)->bf16x8 {
    int col = wc*32 + g*16 + lr;
    int chunk = ks*4 + lg;
    return *(const bf16x8*)&smem[buf*32768 + 16384 + nh*8192 + col*64 + ((chunk ^ (col&7))*8)];
  };

  // prologue: tile0 (4 half-tiles) + B0,A0 of tile1
  stageH(0,0,0); stageH(0,1,0); stageH(0,2,0); stageH(0,3,0);
  stageH(1,2,64); stageH(1,0,64);
  WAITV(4);           // tile0's 8 loads landed; B0(1),A0(1) may fly
  BARM();

  bf16x8 a0[4][2], a1[4][2], bb[2][2];

  for (int kt = 0; kt < 8; ++kt){
    const int buf = kt & 1;
    // ---- P1: quad (mh0,nh0) ----
#pragma unroll
    for (int f=0; f<4; f++)
#pragma unroll
      for (int ks=0; ks<2; ks++) a0[f][ks] = rdA(buf, 0, f, ks);
#pragma unroll
    for (int g=0; g<2; g++)
#pragma unroll
      for (int ks=0; ks<2; ks++) bb[g][ks] = rdB(buf, 0, g, ks);
    if (kt < 7) stageH(buf^1, 1, (kt+1)*64);         // A1(t+1)
    BARM();
    __builtin_amdgcn_s_setprio(1);
#pragma unroll
    for (int ks=0; ks<2; ks++)
#pragma unroll
      for (int f=0; f<4; f++)
#pragma unroll
        for (int g=0; g<2; g++) MFMA16(acc[f][g], a0[f][ks], bb[g][ks]);
    __builtin_amdgcn_s_setprio(0);
    BARM();
    // ---- P2: quad (mh1,nh0) ----
#pragma unroll
    for (int f=0; f<4; f++)
#pragma unroll
      for (int ks=0; ks<2; ks++) a1[f][ks] = rdA(buf, 1, f, ks);
    if (kt < 7) stageH(buf^1, 3, (kt+1)*64);         // B1(t+1)
    BARM();
    __builtin_amdgcn_s_setprio(1);
#pragma unroll
    for (int ks=0; ks<2; ks++)
#pragma unroll
      for (int f=0; f<4; f++)
#pragma unroll
        for (int g=0; g<2; g++) MFMA16(acc[4+f][g], a1[f][ks], bb[g][ks]);
    __builtin_amdgcn_s_setprio(0);
    BARM();
    // ---- P3: quad (mh0,nh1) ----
#pragma unroll
    for (int g=0; g<2; g++)
#pragma unroll
      for (int ks=0; ks<2; ks++) bb[g][ks] = rdB(buf, 1, g, ks);
    if (kt < 6) stageH(buf, 2, (kt+2)*64);           // B0(t+2) — B0 dead after P2
    BARM();
    __builtin_amdgcn_s_setprio(1);
#pragma unroll
    for (int ks=0; ks<2; ks++)
#pragma unroll
      for (int f=0; f<4; f++)
#pragma unroll
        for (int g=0; g<2; g++) MFMA16(acc[f][2+g], a0[f][ks], bb[g][ks]);
    __builtin_amdgcn_s_setprio(0);
    BARM();
    // ---- P4: quad (mh1,nh1) ----
    if (kt < 6) stageH(buf, 0, (kt+2)*64);           // A0(t+2) — A0 dead after P3
    if (kt < 6)      { WAITV(4); }                    // 2 half-tiles (4 loads) may fly
    else if (kt == 6){ WAITV(0); }                    // epilogue drain
    BARM();
    __builtin_amdgcn_s_setprio(1);
#pragma unroll
    for (int ks=0; ks<2; ks++)
#pragma unroll
      for (int f=0; f<4; f++)
#pragma unroll
        for (int g=0; g<2; g++) MFMA16(acc[4+f][2+g], a1[f][ks], bb[g][ks]);
    __builtin_amdgcn_s_setprio(0);
    BARM();
  }

  // ---------------- epilogue: full-tile LDS restage, coalesced global write ----------------
  float bv[2][2];
#pragma unroll
  for (int nh=0; nh<2; nh++)
#pragma unroll
    for (int g=0; g<2; g++)
      bv[nh][g] = bias[n0 + nh*128 + wc*32 + g*16 + lr];

  if (MODE == 0){
    u16* wa = smem;   // logical [256][256] bf16, chunk-XOR swizzled
#pragma unroll
    for (int mh=0; mh<2; mh++)
#pragma unroll
      for (int f=0; f<4; f++)
#pragma unroll
        for (int nh=0; nh<2; nh++)
#pragma unroll
          for (int g=0; g<2; g++)
#pragma unroll
            for (int r=0; r<4; r++){
              int rl = mh*128 + wr*64 + f*16 + lg*4 + r;
              int cl = nh*128 + wc*32 + g*16 + lr;
              wa[rl*256 + (((cl>>3) ^ (rl&31))<<3) + (cl&7)] =
                  f2bf(acc[mh*4+f][nh*2+g][r] + bv[nh][g]);
            }
    BARM();
#pragma unroll
    for (int i=0; i<16; i++){
      int tau = t + 512*i;
      int rl = tau >> 5, ch = tau & 31;
      int m = m0 + rl;
      if (m < M){
        uint4 val = *(const uint4*)&wa[rl*256 + ((ch ^ (rl&31))<<3)];
        int o = n0 + ch*8;
        int part = o >> 9, hq = (o>>6)&7, d = o&63;
        int bb2 = m / NTOK, n = m - bb2*NTOK;
        u16* dst = (part==0) ? q_s : ((part==1) ? k_s : v_s);
        *(uint4*)&dst[((size_t)(bb2*8+hq)*NTOK + n)*64 + d] = val;
      }
    }
  } else {
    float* wf = (float*)smem;  // logical [128][256] f32 per pass
#pragma unroll
    for (int mh=0; mh<2; mh++){
      BARM();
#pragma unroll
      for (int f=0; f<4; f++)
#pragma unroll
        for (int nh=0; nh<2; nh++)
#pragma unroll
          for (int g=0; g<2; g++)
#pragma unroll
            for (int r=0; r<4; r++){
              int rl = wr*64 + f*16 + lg*4 + r;
              int cl = nh*128 + wc*32 + g*16 + lr;
              wf[rl*256 + (((cl>>2) ^ ((rl&31)<<1))<<2) + (cl&3)] =
                  acc[mh*4+f][nh*2+g][r] + bv[nh][g];
            }
      BARM();
#pragma unroll
      for (int i=0; i<16; i++){
        int tau = t + 512*i;
        int rl = tau >> 6, ch = tau & 63;
        int m = m0 + mh*128 + rl;
        if (m < M){
          float4 val = *(const float4*)&wf[rl*256 + ((ch ^ ((rl&31)<<1))<<2)];
          *(float4*)&outF[(size_t)m*512 + n0 + ch*4] = val;
        }
      }
    }
  }
}

// ---------------- K2: partial kv = exp(k)^T @ v, and column sums of exp(k) ----------------
__global__ __launch_bounds__(256) void kv_partial(
    const u16* __restrict__ k_s, const u16* __restrict__ v_s,
    float* __restrict__ kv_p, float* __restrict__ s_p)
{
  __shared__ float smem[18432];
  const int t  = threadIdx.x;
  const int bh = blockIdx.x;
  const int hf = blockIdx.y;
  const size_t base = (size_t)bh * NTOK * 64;
  const int srow = t >> 3;
  const int scol = (t & 7) * 8;
  const int ns = t >> 6;
  const int kg = (t >> 3) & 7;
  const int dg = t & 7;

  float accv[8][8];
#pragma unroll
  for (int a=0;a<8;a++)
#pragma unroll
    for (int c=0;c<8;c++) accv[a][c] = 0.f;
  float s_loc[8];
#pragma unroll
  for (int i=0;i<8;i++) s_loc[i] = 0.f;

  float* ek = smem;
  float* vv = smem + 2048;
  const int n_beg = hf * 1600;
  const int n_end = hf ? NTOK : 1600;

  for (int n0 = n_beg; n0 < n_end; n0 += 32){
    __syncthreads();
    int n = n0 + srow;
    float et[8], vf[8];
    if (n < n_end){
      uint4 kvec = *(const uint4*)&k_s[base + (size_t)n*64 + scol];
      uint4 vvec = *(const uint4*)&v_s[base + (size_t)n*64 + scol];
      const u16* kp = (const u16*)&kvec;
      const u16* vp = (const u16*)&vvec;
#pragma unroll
      for (int i=0;i<8;i++){
        et[i] = __expf(bf2f(kp[i]));
        s_loc[i] += et[i];
        vf[i] = bf2f(vp[i]);
      }
    } else {
#pragma unroll
      for (int i=0;i<8;i++){ et[i]=0.f; vf[i]=0.f; }
    }
    *(float4*)&ek[srow*64 + scol]     = make_float4(et[0],et[1],et[2],et[3]);
    *(float4*)&ek[srow*64 + scol + 4] = make_float4(et[4],et[5],et[6],et[7]);
    *(float4*)&vv[srow*64 + scol]     = make_float4(vf[0],vf[1],vf[2],vf[3]);
    *(float4*)&vv[srow*64 + scol + 4] = make_float4(vf[4],vf[5],vf[6],vf[7]);
    __syncthreads();
#pragma unroll
    for (int i=0;i<8;i++){
      int nl = ns + 4*i;
      float4 e0 = *(const float4*)&ek[nl*64 + kg*8];
      float4 e1 = *(const float4*)&ek[nl*64 + kg*8 + 4];
      float4 v0 = *(const float4*)&vv[nl*64 + dg*8];
      float4 v1 = *(const float4*)&vv[nl*64 + dg*8 + 4];
      float ea[8] = {e0.x,e0.y,e0.z,e0.w,e1.x,e1.y,e1.z,e1.w};
      float va[8] = {v0.x,v0.y,v0.z,v0.w,v1.x,v1.y,v1.z,v1.w};
#pragma unroll
      for (int a=0;a<8;a++)
#pragma unroll
        for (int c=0;c<8;c++) accv[a][c] += ea[a]*va[c];
    }
  }
  __syncthreads();
  float* part_kv = smem;
  float* part_s  = smem + 16384;
#pragma unroll
  for (int a=0;a<8;a++)
#pragma unroll
    for (int c=0;c<8;c++)
      part_kv[(size_t)ns*4096 + (kg*8+a)*64 + dg*8+c] = accv[a][c];
#pragma unroll
  for (int i=0;i<8;i++) part_s[srow*64 + scol + i] = s_loc[i];
  __syncthreads();
  const size_t obase = ((size_t)hf*128 + bh) * 4096;
  for (int i=0;i<16;i++){
    int e = t*16 + i;
    kv_p[obase + e] = part_kv[e] + part_kv[4096+e] + part_kv[8192+e] + part_kv[12288+e];
  }
  if (t < 64){
    float s = 0.f;
    for (int r=0;r<32;r++) s += part_s[r*64 + t];
    s_p[((size_t)hf*128 + bh)*64 + t] = s;
  }
}

// ---------------- K2b: combine halves, divide by S, write kv^T bf16 [bh][d][k] ----------------
__global__ void kv_reduce(const float* __restrict__ kv_p, const float* __restrict__ s_p,
                          u16* __restrict__ kvT){
  const int bh = blockIdx.x, t = threadIdx.x;
  for (int i=0;i<16;i++){
    int e = t*16 + i;
    int k = e >> 6, d = e & 63;
    float v = kv_p[(size_t)bh*4096 + e] + kv_p[(size_t)(128 + bh)*4096 + e];
    float S = s_p[bh*64 + k] + s_p[(128 + bh)*64 + k];
    kvT[(size_t)bh*4096 + d*64 + k] = f2bf(v / S);
  }
}

// ---------------- K3: depthwise conv (K = 2R+1) * q -> ev into out_pre (n>=1 rows) ----------------
template<int R>
__global__ __launch_bounds__(256) void conv_ev(
    const u16* __restrict__ v_s, const u16* __restrict__ q_s,
    const float* __restrict__ wsrc, const float* __restrict__ bsrc,
    int h0, u16* __restrict__ out_pre)
{
  constexpr int KK = 2*R + 1;
  constexpr int TAPS = KK*KK;
  __shared__ __align__(16) u16 vt[KK*56*64];
  const int t = threadIdx.x;
  const int y = blockIdx.x;
  const int hh = blockIdx.y;
  const int b = blockIdx.z;
  const int h = h0 + hh;
  const size_t vbase = ((size_t)(b*8 + h)) * NTOK * 64;

  for (int ry=0; ry<KK; ry++){
    int yy = y - R + ry;
    for (int idx = t; idx < 448; idx += 256){
      uint4 val = make_uint4(0u,0u,0u,0u);
      if (yy >= 0 && yy < 56)
        val = *(const uint4*)&v_s[vbase + (size_t)(1 + yy*56)*64 + idx*8];
      *(uint4*)&vt[ry*3584 + idx*8] = val;
    }
  }
  __syncthreads();
  const int d = t & 63;
  const int xg = t >> 6;
  float wreg[TAPS];
#pragma unroll
  for (int i=0;i<TAPS;i++) wreg[i] = wsrc[(hh*64 + d)*TAPS + i];
  const float bias = bsrc[hh*64 + d];
  float acc[14];
#pragma unroll
  for (int i=0;i<14;i++) acc[i] = bias;
  const int x0 = xg * 14;
#pragma unroll
  for (int ry=0; ry<KK; ry++){
    float rw[14 + 2*R];
#pragma unroll
    for (int i=0; i<14+2*R; i++){
      int xx = x0 - R + i;
      rw[i] = (xx >= 0 && xx < 56) ? bf2f(vt[ry*3584 + xx*64 + d]) : 0.f;
    }
#pragma unroll
    for (int xi=0; xi<14; xi++)
#pragma unroll
      for (int rx=0; rx<KK; rx++)
        acc[xi] += rw[xi+rx] * wreg[ry*KK + rx];
  }
#pragma unroll
  for (int xi=0; xi<14; xi++){
    int x = x0 + xi;
    int n = 1 + y*56 + x;
    float qv = bf2f(q_s[vbase + (size_t)n*64 + d]);
    out_pre[((size_t)b*NTOK + n)*CDIM + h*64 + d] = f2bf(acc[xi] * qv);
  }
}

// ---------------- K4: factor_att = q @ kvT^T ; out_pre = scale*fa + (n>=1 ? ev : 0) ----------------
__global__ __launch_bounds__(256) void fa_add(
    const u16* __restrict__ q_s, const u16* __restrict__ kvT, u16* __restrict__ out_pre)
{
  __shared__ __align__(16) u16 sQ[64*64];
  __shared__ __align__(16) u16 sKV[64*64];
  const int t = threadIdx.x;
  const int nt = blockIdx.x;
  const int h = blockIdx.y;
  const int b = blockIdx.z;
  const int bh = b*8 + h;
  const size_t qbase = (size_t)bh * NTOK * 64;
  const int n0 = nt * 64;
#pragma unroll
  for (int j=0; j<2; j++){
    int qq = t + 256*j;
    int row = qq >> 3, c = qq & 7;
    int nrow = n0 + row; if (nrow > NTOK-1) nrow = NTOK-1;
    uint4 qv = *(const uint4*)&q_s[qbase + (size_t)nrow*64 + c*8];
    *(uint4*)&sQ[row*64 + ((c ^ (row & 7)) * 8)] = qv;
    uint4 kv = *(const uint4*)&kvT[(size_t)bh*4096 + row*64 + c*8];
    *(uint4*)&sKV[row*64 + ((c ^ (row & 7)) * 8)] = kv;
  }
  __syncthreads();
  const int w = t >> 6, l = t & 63, lr = l & 15, lg = l >> 4;
  f32x4 acc[4];
#pragma unroll
  for (int j=0;j<4;j++) acc[j] = (f32x4){0.f,0.f,0.f,0.f};
#pragma unroll
  for (int ks=0; ks<2; ks++){
    int chunk = ks*4 + lg;
    int arow = w*16 + lr;
    bf16x8 af = *(const bf16x8*)&sQ[arow*64 + ((chunk ^ (arow & 7))*8)];
#pragma unroll
    for (int fj=0; fj<4; fj++){
      int col = fj*16 + lr;
      bf16x8 bv = *(const bf16x8*)&sKV[col*64 + ((chunk ^ (col & 7))*8)];
      acc[fj] = __builtin_amdgcn_mfma_f32_16x16x32_bf16(af, bv, acc[fj], 0, 0, 0);
    }
  }
  const float scale = 0.125f;
#pragma unroll
  for (int fj=0; fj<4; fj++){
    int dcol = fj*16 + lr;
#pragma unroll
    for (int r=0; r<4; r++){
      int n = n0 + w*16 + lg*4 + r;
      if (n < NTOK){
        size_t addr = ((size_t)b*NTOK + n)*CDIM + h*64 + dcol;
        float prev = (n >= 1) ? bf2f(out_pre[addr]) : 0.f;
        out_pre[addr] = f2bf(scale*acc[fj][r] + prev);
      }
    }
  }
}

extern "C" void kernel_launch(void* const* d_in, const int* in_sizes, int n_in,
                              void* d_out, int out_size, void* d_ws, size_t ws_size,
                              hipStream_t stream)
{
  const float* x      = (const float*)d_in[0];
  const float* qkv_w  = (const float*)d_in[1];
  const float* qkv_b  = (const float*)d_in[2];
  const float* proj_w = (const float*)d_in[3];
  const float* proj_b = (const float*)d_in[4];
  const float* w3 = (const float*)d_in[5];
  const float* b3 = (const float*)d_in[6];
  const float* w5 = (const float*)d_in[7];
  const float* b5 = (const float*)d_in[8];
  const float* w7 = (const float*)d_in[9];
  const float* b7 = (const float*)d_in[10];
  float* out = (float*)d_out;

  char* ws = (char*)d_ws;
  size_t off = 0;
  auto alloc = [&](size_t bytes) -> void* {
    void* p = ws + off;
    off += (bytes + 255) & ~(size_t)255;
    return p;
  };
  u16*   x_bf     = (u16*)alloc((size_t)MT*512*2);        // reused as out_pre after qkv GEMM
  u16*   qkvw_bf  = (u16*)alloc((size_t)1536*512*2);
  u16*   projw_bf = (u16*)alloc((size_t)512*512*2);
  u16*   q_s      = (u16*)alloc((size_t)128*NTOK*64*2);
  u16*   k_s      = (u16*)alloc((size_t)128*NTOK*64*2);
  u16*   v_s      = (u16*)alloc((size_t)128*NTOK*64*2);
  u16*   kvT      = (u16*)alloc((size_t)128*4096*2);
  float* kv_p     = (float*)alloc((size_t)2*128*4096*4);
  float* s_p      = (float*)alloc((size_t)2*128*64*4);
  u16*   out_pre  = x_bf;

  { int n4 = (MT*512)/4;   cvt_kernel<<<(n4+255)/256, 256, 0, stream>>>(x, x_bf, n4); }
  { int n4 = (1536*512)/4; cvt_kernel<<<(n4+255)/256, 256, 0, stream>>>(qkv_w, qkvw_bf, n4); }
  { int n4 = (512*512)/4;  cvt_kernel<<<(n4+255)/256, 256, 0, stream>>>(proj_w, projw_bf, n4); }

  // qkv: M=50192, N=1536, K=512 — 8-phase 256x256
  gemm8<0><<<dim3(6, 197), 512, 0, stream>>>(x_bf, qkvw_bf, qkv_b, q_s, k_s, v_s, nullptr, MT);

  kv_partial<<<dim3(128, 2), 256, 0, stream>>>(k_s, v_s, kv_p, s_p);
  kv_reduce<<<128, 256, 0, stream>>>(kv_p, s_p, kvT);
  conv_ev<1><<<dim3(56, 2, 16), 256, 0, stream>>>(v_s, q_s, w3, b3, 0, out_pre);
  conv_ev<2><<<dim3(56, 3, 16), 256, 0, stream>>>(v_s, q_s, w5, b5, 2, out_pre);
  conv_ev<3><<<dim3(56, 3, 16), 256, 0, stream>>>(v_s, q_s, w7, b7, 5, out_pre);
  fa_add<<<dim3(50, 8, 16), 256, 0, stream>>>(q_s, kvT, out_pre);

  // proj: M=50192, N=512, K=512 — 8-phase 256x256, fp32 out
  gemm8<1><<<dim3(2, 197), 512, 0, stream>>>(out_pre, projw_bf, proj_b, nullptr, nullptr, nullptr, out, MT);
}

// Round 4
// 378.213 us; speedup vs baseline: 1.2349x; 1.2349x over previous
//
#include <hip/hip_runtime.h>
#include <stdint.h>

#define NHEADS 8
#define NTOK   3137
#define BATCH  16
#define CDIM   512
#define MT     (BATCH*NTOK)   // 50192

typedef unsigned short u16;
typedef float f32x4  __attribute__((ext_vector_type(4)));
typedef short bf16x8 __attribute__((ext_vector_type(8)));

__device__ __forceinline__ float bf2f(u16 u){
  union { uint32_t i; float f; } x; x.i = ((uint32_t)u) << 16; return x.f;
}
__device__ __forceinline__ u16 f2bf(float f){
  union { float f; uint32_t i; } x; x.f = f;
  uint32_t r = x.i + 0x7fffu + ((x.i >> 16) & 1u);
  return (u16)(r >> 16);
}
__device__ __forceinline__ void async_ld16(void* lds, const void* g){
  __builtin_amdgcn_global_load_lds((const __attribute__((address_space(1))) void*)g,
                                   (__attribute__((address_space(3))) void*)lds, 16, 0, 0);
}
#define MFMA16(d,a,b) d = __builtin_amdgcn_mfma_f32_16x16x32_bf16(a,b,d,0,0,0)

// ---------------- K0: fp32 -> bf16 cast ----------------
__global__ void cvt_kernel(const float* __restrict__ src, u16* __restrict__ dst, int n4){
  int i = blockIdx.x * blockDim.x + threadIdx.x;
  if (i < n4){
    float4 v = ((const float4*)src)[i];
    uint32_t lo = ((uint32_t)f2bf(v.y) << 16) | f2bf(v.x);
    uint32_t hi = ((uint32_t)f2bf(v.w) << 16) | f2bf(v.z);
    ((uint2*)dst)[i] = make_uint2(lo, hi);
  }
}

// ---------------- GEMM (round-2 winner): 2-phase double-buffered pipeline ----------------
// C[m][o] = sum_k A[m][k]*Bw[o][k] + bias[o], K=512, BK=64.
// STAGE(next) -> compute(cur) -> one __syncthreads per iter. T1 bijective XCD swizzle.
// T2 via pre-swizzled global source. Coalesced epilogue through LDS.
// MODE 0: scatter bf16 to q/k/v [b*8+h][n][64].  MODE 1: fp32 out [m][512].
template<int BM,int BN,int WM,int WN,int MODE>
__global__ __launch_bounds__(WM*WN*64, 2) void gemm2(
    const u16* __restrict__ A, const u16* __restrict__ Bw, const float* __restrict__ bias,
    u16* __restrict__ q_s, u16* __restrict__ k_s, u16* __restrict__ v_s,
    float* __restrict__ outF, int M)
{
  constexpr int THREADS = WM*WN*64;
  constexpr int MF = BM/(WM*16);
  constexpr int NF = BN/(WN*16);
  constexpr int WROWS = BM/WM;
  constexpr int WCOLS = BN/WN;
  __shared__ __align__(16) u16 smem[2*(BM+BN)*64];

  const int t = threadIdx.x;
  const int w = t >> 6, l = t & 63;
  const int wr = w / WN, wc = w % WN;
  const int lr = l & 15, lg = l >> 4;

  const int nx = gridDim.x;
  const int nwg = nx * gridDim.y;
  const int orig = blockIdx.y * nx + blockIdx.x;
  const int q8 = nwg >> 3, r8 = nwg & 7;
  const int xcd = orig & 7;
  const int wgid = (xcd < r8 ? xcd*(q8+1) : r8*(q8+1) + (xcd-r8)*q8) + (orig >> 3);
  const int n0 = (wgid % nx) * BN;
  const int m0 = (wgid / nx) * BM;

  f32x4 acc[MF][NF];
#pragma unroll
  for (int i=0;i<MF;i++)
#pragma unroll
    for (int j=0;j<NF;j++) acc[i][j] = (f32x4){0.f,0.f,0.f,0.f};

  auto stage = [&](int bi, int k0){
    u16* da = smem + bi*(BM*64);
    u16* db = smem + 2*BM*64 + bi*(BN*64);
#pragma unroll
    for (int j=0;j<(BM*8)/THREADS;j++){
      int qc = t + THREADS*j;
      int R = qc >> 3, c = qc & 7;
      int cs = (c ^ (R & 7)) * 8;
      int ar = m0 + R; if (ar > M-1) ar = M-1;
      async_ld16(&da[qc*8], &A[(size_t)ar*512 + k0 + cs]);
    }
#pragma unroll
    for (int j=0;j<(BN*8)/THREADS;j++){
      int qc = t + THREADS*j;
      int R = qc >> 3, c = qc & 7;
      int cs = (c ^ (R & 7)) * 8;
      async_ld16(&db[qc*8], &Bw[(size_t)(n0+R)*512 + k0 + cs]);
    }
  };

  stage(0, 0);
  __syncthreads();
  int cur = 0;
  for (int kt = 0; kt < 8; ++kt){
    if (kt < 7) stage(cur ^ 1, (kt+1)*64);
    const u16* a_base = smem + cur*(BM*64);
    const u16* b_base = smem + 2*BM*64 + cur*(BN*64);
    __builtin_amdgcn_s_setprio(1);
#pragma unroll
    for (int ks=0; ks<2; ks++){
      bf16x8 af[MF], bfv[NF];
      int chunk = ks*4 + lg;
#pragma unroll
      for (int fi=0;fi<MF;fi++){
        int row = wr*WROWS + fi*16 + lr;
        af[fi] = *(const bf16x8*)&a_base[row*64 + ((chunk ^ (row & 7))*8)];
      }
#pragma unroll
      for (int fj=0;fj<NF;fj++){
        int col = wc*WCOLS + fj*16 + lr;
        bfv[fj] = *(const bf16x8*)&b_base[col*64 + ((chunk ^ (col & 7))*8)];
      }
#pragma unroll
      for (int fi=0;fi<MF;fi++)
#pragma unroll
        for (int fj=0;fj<NF;fj++)
          acc[fi][fj] = __builtin_amdgcn_mfma_f32_16x16x32_bf16(af[fi], bfv[fj], acc[fi][fj], 0, 0, 0);
    }
    __builtin_amdgcn_s_setprio(0);
    __syncthreads();
    cur ^= 1;
  }

  if (MODE == 0){
    u16* warea = smem + w * (WROWS*WCOLS);
    float bvv[NF];
#pragma unroll
    for (int fj=0;fj<NF;fj++) bvv[fj] = bias[n0 + wc*WCOLS + fj*16 + lr];
#pragma unroll
    for (int fi=0;fi<MF;fi++)
#pragma unroll
      for (int fj=0;fj<NF;fj++)
#pragma unroll
        for (int r=0;r<4;r++)
          warea[(fi*16 + lg*4 + r)*WCOLS + fj*16 + lr] = f2bf(acc[fi][fj][r] + bvv[fj]);
    __syncthreads();
    const int colo = n0 + wc*WCOLS;
    const int part = colo >> 9;
    const int hq   = (colo >> 6) & 7;
    u16* dst = (part == 0) ? q_s : ((part == 1) ? k_s : v_s);
    const int rsub = l >> 3;
    const int csub = (l & 7) * 8;
#pragma unroll
    for (int pass=0; pass<WROWS/8; ++pass){
      int rl = pass*8 + rsub;
      int m = m0 + wr*WROWS + rl;
      if (m < M){
        int bb = m / NTOK;
        int n  = m - bb*NTOK;
        uint4 vv = *(const uint4*)&warea[rl*WCOLS + csub];
        *(uint4*)&dst[((size_t)(bb*8 + hq)*NTOK + n)*64 + csub] = vv;
      }
    }
  } else {
    float* warea = (float*)smem + w * (WROWS*WCOLS);
    float bvv[NF];
#pragma unroll
    for (int fj=0;fj<NF;fj++) bvv[fj] = bias[n0 + wc*WCOLS + fj*16 + lr];
#pragma unroll
    for (int fi=0;fi<MF;fi++)
#pragma unroll
      for (int fj=0;fj<NF;fj++)
#pragma unroll
        for (int r=0;r<4;r++)
          warea[(fi*16 + lg*4 + r)*WCOLS + fj*16 + lr] = acc[fi][fj][r] + bvv[fj];
    __syncthreads();
    const int colo = n0 + wc*WCOLS;
    const int rsub = l >> 4;
    const int csub = (l & 15) * 4;
#pragma unroll
    for (int pass=0; pass<WROWS/4; ++pass){
      int rl = pass*4 + rsub;
      int m = m0 + wr*WROWS + rl;
      if (m < M){
        float4 vv = *(const float4*)&warea[rl*WCOLS + csub];
        *(float4*)&outF[(size_t)m*512 + colo + csub] = vv;
      }
    }
  }
}

// ---------------- K2: partial kv = exp(k)^T @ v, column sums of exp(k); 4-way n-split ----------------
__global__ __launch_bounds__(256) void kv_partial(
    const u16* __restrict__ k_s, const u16* __restrict__ v_s,
    float* __restrict__ kv_p, float* __restrict__ s_p)
{
  __shared__ float smem[18432];
  const int t  = threadIdx.x;
  const int bh = blockIdx.x;
  const int hf = blockIdx.y;            // 0..3
  const size_t base = (size_t)bh * NTOK * 64;
  const int srow = t >> 3;
  const int scol = (t & 7) * 8;
  const int ns = t >> 6;
  const int kg = (t >> 3) & 7;
  const int dg = t & 7;

  float accv[8][8];
#pragma unroll
  for (int a=0;a<8;a++)
#pragma unroll
    for (int c=0;c<8;c++) accv[a][c] = 0.f;
  float s_loc[8];
#pragma unroll
  for (int i=0;i<8;i++) s_loc[i] = 0.f;

  float* ek = smem;
  float* vv = smem + 2048;
  const int n_beg = hf * 800;
  const int n_end = (hf == 3) ? NTOK : (n_beg + 800);

  for (int n0 = n_beg; n0 < n_end; n0 += 32){
    __syncthreads();
    int n = n0 + srow;
    float et[8], vf[8];
    if (n < n_end){
      uint4 kvec = *(const uint4*)&k_s[base + (size_t)n*64 + scol];
      uint4 vvec = *(const uint4*)&v_s[base + (size_t)n*64 + scol];
      const u16* kp = (const u16*)&kvec;
      const u16* vp = (const u16*)&vvec;
#pragma unroll
      for (int i=0;i<8;i++){
        et[i] = __expf(bf2f(kp[i]));
        s_loc[i] += et[i];
        vf[i] = bf2f(vp[i]);
      }
    } else {
#pragma unroll
      for (int i=0;i<8;i++){ et[i]=0.f; vf[i]=0.f; }
    }
    *(float4*)&ek[srow*64 + scol]     = make_float4(et[0],et[1],et[2],et[3]);
    *(float4*)&ek[srow*64 + scol + 4] = make_float4(et[4],et[5],et[6],et[7]);
    *(float4*)&vv[srow*64 + scol]     = make_float4(vf[0],vf[1],vf[2],vf[3]);
    *(float4*)&vv[srow*64 + scol + 4] = make_float4(vf[4],vf[5],vf[6],vf[7]);
    __syncthreads();
#pragma unroll
    for (int i=0;i<8;i++){
      int nl = ns + 4*i;
      float4 e0 = *(const float4*)&ek[nl*64 + kg*8];
      float4 e1 = *(const float4*)&ek[nl*64 + kg*8 + 4];
      float4 v0 = *(const float4*)&vv[nl*64 + dg*8];
      float4 v1 = *(const float4*)&vv[nl*64 + dg*8 + 4];
      float ea[8] = {e0.x,e0.y,e0.z,e0.w,e1.x,e1.y,e1.z,e1.w};
      float va[8] = {v0.x,v0.y,v0.z,v0.w,v1.x,v1.y,v1.z,v1.w};
#pragma unroll
      for (int a=0;a<8;a++)
#pragma unroll
        for (int c=0;c<8;c++) accv[a][c] += ea[a]*va[c];
    }
  }
  __syncthreads();
  float* part_kv = smem;
  float* part_s  = smem + 16384;
#pragma unroll
  for (int a=0;a<8;a++)
#pragma unroll
    for (int c=0;c<8;c++)
      part_kv[(size_t)ns*4096 + (kg*8+a)*64 + dg*8+c] = accv[a][c];
#pragma unroll
  for (int i=0;i<8;i++) part_s[srow*64 + scol + i] = s_loc[i];
  __syncthreads();
  const size_t obase = ((size_t)hf*128 + bh) * 4096;
  for (int i=0;i<16;i++){
    int e = t*16 + i;
    kv_p[obase + e] = part_kv[e] + part_kv[4096+e] + part_kv[8192+e] + part_kv[12288+e];
  }
  if (t < 64){
    float s = 0.f;
    for (int r=0;r<32;r++) s += part_s[r*64 + t];
    s_p[((size_t)hf*128 + bh)*64 + t] = s;
  }
}

// ---------------- K2b: combine quarters, divide by S, write kv^T bf16 [bh][d][k] ----------------
__global__ void kv_reduce(const float* __restrict__ kv_p, const float* __restrict__ s_p,
                          u16* __restrict__ kvT){
  const int bh = blockIdx.x, t = threadIdx.x;
  for (int i=0;i<16;i++){
    int e = t*16 + i;
    int k = e >> 6, d = e & 63;
    float v = 0.f, S = 0.f;
#pragma unroll
    for (int hf=0; hf<4; hf++){
      v += kv_p[(size_t)(hf*128 + bh)*4096 + e];
      S += s_p[(hf*128 + bh)*64 + k];
    }
    kvT[(size_t)bh*4096 + d*64 + k] = f2bf(v / S);
  }
}

// ---------------- K3: fused depthwise conv + factor_att for one (b,h,y) row ----------------
// out[n][h*64+d] = scale*fa[n][d] + conv[n][d]*q[n][d]   for n = 1+y*56 .. +55
// fa via MFMA (q-tile 64x64 x kvT 64x64); fa f32 tile overlays sQ/sKV LDS after use.
template<int R>
__global__ __launch_bounds__(256) void conv_fa(
    const u16* __restrict__ v_s, const u16* __restrict__ q_s,
    const u16* __restrict__ kvT,
    const float* __restrict__ wsrc, const float* __restrict__ bsrc,
    int h0, u16* __restrict__ out_pre)
{
  constexpr int KK = 2*R + 1;
  constexpr int TAPS = KK*KK;
  __shared__ __align__(16) u16 smem[8192 + KK*3584];   // [0,8192)u16: sQ|sKV, later fa f32
  u16* vt = smem + 8192;
  const int t = threadIdx.x;
  const int y  = blockIdx.x;
  const int hh = blockIdx.y;
  const int b  = blockIdx.z;
  const int h  = h0 + hh;
  const int bh = b*8 + h;
  const size_t base = (size_t)bh * NTOK * 64;
  const int n0 = 1 + y*56;

  // stage sQ (rows n0..n0+63, clamped) and sKV, async, pre-swizzled source
#pragma unroll
  for (int j=0;j<2;j++){
    int qq = t + 256*j;
    int row = qq >> 3, c = qq & 7;
    int cs = (c ^ (row & 7)) * 8;
    int n = n0 + row; if (n > NTOK-1) n = NTOK-1;
    async_ld16(&smem[qq*8], &q_s[base + (size_t)n*64 + cs]);
    async_ld16(&smem[4096 + qq*8], &kvT[(size_t)bh*4096 + row*64 + cs]);
  }
  // stage v window (zero-padded y edges)
  for (int ry=0; ry<KK; ry++){
    int yy = y - R + ry;
    for (int idx = t; idx < 448; idx += 256){
      uint4 val = make_uint4(0u,0u,0u,0u);
      if (yy >= 0 && yy < 56)
        val = *(const uint4*)&v_s[base + (size_t)(1 + yy*56)*64 + idx*8];
      *(uint4*)&vt[ry*3584 + idx*8] = val;
    }
  }
  __syncthreads();

  // --- fa MFMA: rows = tokens (n0+r), cols = d ---
  const int w = t >> 6, l = t & 63;
  const int lr = l & 15, lg = l >> 4;
  f32x4 fac[4];
#pragma unroll
  for (int j=0;j<4;j++) fac[j] = (f32x4){0.f,0.f,0.f,0.f};
#pragma unroll
  for (int ks=0; ks<2; ks++){
    int chunk = ks*4 + lg;
    int arow = w*16 + lr;
    bf16x8 af = *(const bf16x8*)&smem[arow*64 + ((chunk ^ (arow & 7))*8)];
#pragma unroll
    for (int fj=0; fj<4; fj++){
      int col = fj*16 + lr;
      bf16x8 bv = *(const bf16x8*)&smem[4096 + col*64 + ((chunk ^ (col & 7))*8)];
      MFMA16(fac[fj], af, bv);
    }
  }

  // --- conv compute (vt) ---
  const int d = l;
  const int xg = w;
  float wreg[TAPS];
#pragma unroll
  for (int i=0;i<TAPS;i++) wreg[i] = wsrc[(hh*64 + d)*TAPS + i];
  const float bias = bsrc[hh*64 + d];
  float creg[14];
#pragma unroll
  for (int i=0;i<14;i++) creg[i] = bias;
  const int x0 = xg * 14;
#pragma unroll
  for (int ry=0; ry<KK; ry++){
    float rw[14 + 2*R];
#pragma unroll
    for (int i=0; i<14+2*R; i++){
      int xx = x0 - R + i;
      rw[i] = (xx >= 0 && xx < 56) ? bf2f(vt[ry*3584 + xx*64 + d]) : 0.f;
    }
#pragma unroll
    for (int xi=0; xi<14; xi++)
#pragma unroll
      for (int rx=0; rx<KK; rx++)
        creg[xi] += rw[xi+rx] * wreg[ry*KK + rx];
  }

  // read q values for combine from sQ (before fa overlays it)
  float qv[14];
#pragma unroll
  for (int xi=0; xi<14; xi++){
    int row = x0 + xi;
    int chunk = d >> 3, e = d & 7;
    qv[xi] = bf2f(smem[row*64 + ((chunk ^ (row & 7))*8) + e]);
  }

  __syncthreads();                       // all sQ/sKV reads done
  float* fa = (float*)smem;              // overlay [64][64] f32
#pragma unroll
  for (int fj=0; fj<4; fj++)
#pragma unroll
    for (int r=0; r<4; r++)
      fa[(w*16 + lg*4 + r)*64 + fj*16 + lr] = 0.125f * fac[fj][r];
  __syncthreads();

  // combine + write
#pragma unroll
  for (int xi=0; xi<14; xi++){
    int nn = n0 + x0 + xi;
    out_pre[((size_t)b*NTOK + nn)*CDIM + h*64 + d] =
        f2bf(fa[(x0 + xi)*64 + d] + creg[xi]*qv[xi]);
  }
}

// ---------------- K4: n=0 row: out = scale * q[0] @ kvT^T ----------------
__global__ void fa0_kernel(const u16* __restrict__ q_s, const u16* __restrict__ kvT,
                           u16* __restrict__ out_pre){
  const int b = blockIdx.x, t = threadIdx.x;   // 512 threads
  const int h = t >> 6, d = t & 63;
  const int bh = b*8 + h;
  float s = 0.f;
#pragma unroll
  for (int k=0; k<64; k++)
    s += bf2f(q_s[(size_t)bh*NTOK*64 + k]) * bf2f(kvT[(size_t)bh*4096 + d*64 + k]);
  out_pre[(size_t)b*NTOK*CDIM + h*64 + d] = f2bf(0.125f * s);
}

extern "C" void kernel_launch(void* const* d_in, const int* in_sizes, int n_in,
                              void* d_out, int out_size, void* d_ws, size_t ws_size,
                              hipStream_t stream)
{
  const float* x      = (const float*)d_in[0];
  const float* qkv_w  = (const float*)d_in[1];
  const float* qkv_b  = (const float*)d_in[2];
  const float* proj_w = (const float*)d_in[3];
  const float* proj_b = (const float*)d_in[4];
  const float* w3 = (const float*)d_in[5];
  const float* b3 = (const float*)d_in[6];
  const float* w5 = (const float*)d_in[7];
  const float* b5 = (const float*)d_in[8];
  const float* w7 = (const float*)d_in[9];
  const float* b7 = (const float*)d_in[10];
  float* out = (float*)d_out;

  char* ws = (char*)d_ws;
  size_t off = 0;
  auto alloc = [&](size_t bytes) -> void* {
    void* p = ws + off;
    off += (bytes + 255) & ~(size_t)255;
    return p;
  };
  u16*   x_bf     = (u16*)alloc((size_t)MT*512*2);        // reused as out_pre after qkv GEMM
  u16*   qkvw_bf  = (u16*)alloc((size_t)1536*512*2);
  u16*   projw_bf = (u16*)alloc((size_t)512*512*2);
  u16*   q_s      = (u16*)alloc((size_t)128*NTOK*64*2);
  u16*   k_s      = (u16*)alloc((size_t)128*NTOK*64*2);
  u16*   v_s      = (u16*)alloc((size_t)128*NTOK*64*2);
  u16*   kvT      = (u16*)alloc((size_t)128*4096*2);
  float* kv_p     = (float*)alloc((size_t)4*128*4096*4);
  float* s_p      = (float*)alloc((size_t)4*128*64*4);
  u16*   out_pre  = x_bf;

  { int n4 = (MT*512)/4;   cvt_kernel<<<(n4+255)/256, 256, 0, stream>>>(x, x_bf, n4); }
  { int n4 = (1536*512)/4; cvt_kernel<<<(n4+255)/256, 256, 0, stream>>>(qkv_w, qkvw_bf, n4); }
  { int n4 = (512*512)/4;  cvt_kernel<<<(n4+255)/256, 256, 0, stream>>>(proj_w, projw_bf, n4); }

  // qkv: M=50192, N=1536, K=512 — 256x256 2-phase (round-2 winner)
  gemm2<256,256,2,4,0><<<dim3(6, 197), 512, 0, stream>>>(
      x_bf, qkvw_bf, qkv_b, q_s, k_s, v_s, nullptr, MT);

  kv_partial<<<dim3(128, 4), 256, 0, stream>>>(k_s, v_s, kv_p, s_p);
  kv_reduce<<<128, 256, 0, stream>>>(kv_p, s_p, kvT);
  fa0_kernel<<<16, 512, 0, stream>>>(q_s, kvT, out_pre);

  conv_fa<1><<<dim3(56, 2, 16), 256, 0, stream>>>(v_s, q_s, kvT, w3, b3, 0, out_pre);
  conv_fa<2><<<dim3(56, 3, 16), 256, 0, stream>>>(v_s, q_s, kvT, w5, b5, 2, out_pre);
  conv_fa<3><<<dim3(56, 3, 16), 256, 0, stream>>>(v_s, q_s, kvT, w7, b7, 5, out_pre);

  // proj: M=50192, N=512, K=512 — 128x128 2-phase
  gemm2<128,128,2,2,1><<<dim3(4, 393), 256, 0, stream>>>(
      out_pre, projw_bf, proj_b, nullptr, nullptr, nullptr, out, MT);
}